// Round 6
// baseline (147.669 us; speedup 1.0000x reference)
//
#include <hip/hip_runtime.h>
#include <stdint.h>
#include <stddef.h>

#define Tdim 4096
#define Hdim 2048
#define KHALF (Hdim / 2)

typedef short short8 __attribute__((ext_vector_type(8)));
typedef float floatx4 __attribute__((ext_vector_type(4)));

// RNE fp32 -> bf16 bit pattern
__device__ __forceinline__ unsigned short f2bf(float f) {
  uint32_t u = __float_as_uint(f);
  u += 0x7fffu + ((u >> 16) & 1u);
  return (unsigned short)(u >> 16);
}

__device__ __forceinline__ float bf2f(unsigned short u) {
  return __uint_as_float(((uint32_t)u) << 16);
}

// async global->LDS, 16B per lane. LDS dest is wave-uniform base + lane*16.
__device__ __forceinline__ void load_lds16(const void* g, void* l) {
  __builtin_amdgcn_global_load_lds(
      (__attribute__((address_space(1))) unsigned int*)(uintptr_t)g,
      (__attribute__((address_space(3))) unsigned int*)l,
      16, 0, 0);
}

__device__ __forceinline__ float tanh_fast(float z) {
  // tanh(z) = 1 - 2/(exp(2z)+1); safe for all z
  float e = __expf(z + z);
  return 1.0f - __fdividef(2.0f, e + 1.0f);
}

// aligned LDS vector read (forces ds_read_b128)
__device__ __forceinline__ short8 lds_read8(const unsigned short* p) {
  return *(const short8*)__builtin_assume_aligned(p, 16);
}

// ---- fused convert: blocks [0,4096) cast x -> bf16; blocks [4096,5120)
// transpose+cast b (HxH fp32, [k][n]) -> bt bf16 (N x K, [n][k]) ----
__global__ __launch_bounds__(256) void cvt_kernel(const float* __restrict__ x,
                                                  const float* __restrict__ b,
                                                  unsigned short* __restrict__ xbf,
                                                  unsigned short* __restrict__ bt) {
  __shared__ unsigned short tile[64 * 65];
  const int t = threadIdx.x;
  if (blockIdx.x < 4096) {
    size_t i = ((size_t)blockIdx.x * 256 + t) * 8;
    float4 f0 = *(const float4*)(x + i);
    float4 f1 = *(const float4*)(x + i + 4);
    union { unsigned short u[8]; uint4 v; } o;
    o.u[0] = f2bf(f0.x); o.u[1] = f2bf(f0.y); o.u[2] = f2bf(f0.z); o.u[3] = f2bf(f0.w);
    o.u[4] = f2bf(f1.x); o.u[5] = f2bf(f1.y); o.u[6] = f2bf(f1.z); o.u[7] = f2bf(f1.w);
    *(uint4*)(xbf + i) = o.v;
    return;
  }
  const int tb = blockIdx.x - 4096;
  const int bj = tb & 31;  // n block
  const int bi = tb >> 5;  // k block
  {
    const int r0 = t >> 4, c4 = (t & 15) * 4;
#pragma unroll
    for (int p = 0; p < 4; ++p) {
      int r = r0 + p * 16;
      float4 v = *(const float4*)(b + (size_t)(bi * 64 + r) * Hdim + bj * 64 + c4);
      tile[r * 65 + c4 + 0] = f2bf(v.x);
      tile[r * 65 + c4 + 1] = f2bf(v.y);
      tile[r * 65 + c4 + 2] = f2bf(v.z);
      tile[r * 65 + c4 + 3] = f2bf(v.w);
    }
  }
  __syncthreads();
  {
    const int n = t >> 2, kq = (t & 3) * 16;
    union { unsigned short u[16]; uint4 v[2]; } o;
#pragma unroll
    for (int q = 0; q < 16; ++q) o.u[q] = tile[(kq + q) * 65 + n];
    uint4* dst = (uint4*)(bt + (size_t)(bj * 64 + n) * Hdim + bi * 64 + kq);
    dst[0] = o.v[0];
    dst[1] = o.v[1];
  }
}

// ---- split-K GEMM: S_kz(MxN bf16) = A(M x K/2 bf16) * B_half, kz = blockIdx.z.
// 128x128 tile, BK=64, 4 waves 2x2 of 64x64 (4x4 frags of 16x16x32 MFMA).
// Split-K=2 doubles the grid to 1024 blocks -> 4 blocks/CU; at round-5's
// 2 blocks/CU ~50% of cycles were idle on the barrier drain (m114: implicit
// cross-block overlap needs >=3 resident blocks). Partials stored bf16 so
// total write traffic stays 33.5 MB (fp32 partials would add +67 MB net).
// XOR-swizzled LDS: slot (row, chunk c) holds global chunk (c ^ (row&7));
// swizzle applied to the GLOBAL source column so the wave-uniform contiguous
// global_load_lds dest is preserved; fragment reads XOR the same term
// (round-5: SQ_LDS_BANK_CONFLICT 1.26e7 -> 0).
__global__ __launch_bounds__(256) void gemm_bt_kernel(const unsigned short* __restrict__ A,
                                                      const unsigned short* __restrict__ Bt,
                                                      unsigned short* __restrict__ S0,
                                                      unsigned short* __restrict__ S1) {
  __shared__ unsigned short sA[128 * 64];
  __shared__ unsigned short sB[128 * 64];
  const int tid = threadIdx.x;
  const int bn = blockIdx.x, bm = blockIdx.y, kz = blockIdx.z;
  const int wave = tid >> 6, lane = tid & 63;
  const int wm = (wave >> 1) * 64, wn = (wave & 1) * 64;
  const int l15 = lane & 15, quad = lane >> 4;
  const int l7 = l15 & 7;  // row&7 of every row this lane reads fragments from

  // staging: thread tid fills LDS slot (row=tid>>3, chunk=tid&7); fetches
  // global chunk (tid&7) ^ (row&7). Row advances by 32 per c-chunk (0 mod 8),
  // so the XOR term is constant per thread.
  const int swz = ((tid & 7) ^ ((tid >> 3) & 7)) * 8;
  const int kbase = kz * KHALF;
  const unsigned short* aSrc = A + ((size_t)(bm * 128 + (tid >> 3)) * Hdim + kbase + swz);
  const unsigned short* bSrc = Bt + ((size_t)(bn * 128 + (tid >> 3)) * Hdim + kbase + swz);
  unsigned short* aDst = &sA[tid * 8];
  unsigned short* bDst = &sB[tid * 8];

  floatx4 acc[4][4] = {};

  for (int k0 = 0; k0 < KHALF; k0 += 64) {
#pragma unroll
    for (int c = 0; c < 4; ++c)
      load_lds16(aSrc + (size_t)c * 32 * Hdim + k0, aDst + c * 2048);
#pragma unroll
    for (int c = 0; c < 4; ++c)
      load_lds16(bSrc + (size_t)c * 32 * Hdim + k0, bDst + c * 2048);
    __syncthreads();
#pragma unroll
    for (int kk = 0; kk < 64; kk += 32) {
      // fragment chunk index = kk/8 + quad, swizzled by row&7 (= l15&7)
      const int coff = (((kk >> 3) + quad) ^ l7) * 8;
      short8 av[4], bv[4];
#pragma unroll
      for (int i = 0; i < 4; ++i)
        av[i] = lds_read8(&sA[(wm + i * 16 + l15) * 64 + coff]);
#pragma unroll
      for (int j = 0; j < 4; ++j)
        bv[j] = lds_read8(&sB[(wn + j * 16 + l15) * 64 + coff]);
#pragma unroll
      for (int i = 0; i < 4; ++i)
#pragma unroll
        for (int j = 0; j < 4; ++j)
          acc[i][j] = __builtin_amdgcn_mfma_f32_16x16x32_bf16(av[i], bv[j], acc[i][j], 0, 0, 0);
    }
    __syncthreads();
  }

  // C/D layout: col = lane&15, row = quad*4 + r (m89/m91-verified)
  unsigned short* Sout = kz ? S1 : S0;
  const int row0 = bm * 128 + wm + quad * 4;
  const int col0 = bn * 128 + wn + l15;
#pragma unroll
  for (int i = 0; i < 4; ++i)
#pragma unroll
    for (int j = 0; j < 4; ++j)
#pragma unroll
      for (int r = 0; r < 4; ++r)
        Sout[(size_t)(row0 + i * 16 + r) * Hdim + (col0 + j * 16)] = f2bf(acc[i][j][r]);
}

// ---- windowed parallel "scan": |a| <= 0.03125 so influence of h_{t-8} < 1e-12.
// s_t = S0_t + S1_t (bf16 partials summed in fp32). ----
__global__ __launch_bounds__(256) void scan_kernel(const unsigned short* __restrict__ S0,
                                                   const unsigned short* __restrict__ S1,
                                                   const float* __restrict__ a,
                                                   float* __restrict__ out) {
  const int j = blockIdx.x * 256 + threadIdx.x;  // column
  const int t0 = blockIdx.y * 32;                // output chunk start
  const float aj = a[j];
  float h = 0.0f;
  int ts = t0 - 8;
  if (ts < 0) ts = 0;
  for (int t = ts; t < t0; ++t) {  // warm-up window (exact for t0==0)
    size_t idx = (size_t)t * Hdim + j;
    h = tanh_fast(fmaf(aj, h, bf2f(S0[idx]) + bf2f(S1[idx])));
  }
#pragma unroll
  for (int t = t0; t < t0 + 32; ++t) {
    size_t idx = (size_t)t * Hdim + j;
    h = tanh_fast(fmaf(aj, h, bf2f(S0[idx]) + bf2f(S1[idx])));
    out[idx] = h;
  }
}

extern "C" void kernel_launch(void* const* d_in, const int* in_sizes, int n_in,
                              void* d_out, int out_size, void* d_ws, size_t ws_size,
                              hipStream_t stream) {
  const float* x = (const float*)d_in[0];
  const float* a = (const float*)d_in[1];
  const float* b = (const float*)d_in[2];
  float* out = (float*)d_out;

  unsigned short* ws = (unsigned short*)d_ws;
  unsigned short* s0 = ws;                                  // 16.8 MB
  unsigned short* s1 = s0 + (size_t)Tdim * Hdim;            // 16.8 MB
  unsigned short* xbf = s1 + (size_t)Tdim * Hdim;           // 16.8 MB
  unsigned short* btb = xbf + (size_t)Tdim * Hdim;          // 8.4 MB

  hipLaunchKernelGGL(cvt_kernel, dim3(4096 + (Hdim / 64) * (Hdim / 64)), dim3(256), 0, stream,
                     x, b, xbf, btb);
  hipLaunchKernelGGL(gemm_bt_kernel, dim3(Hdim / 128, Tdim / 128, 2), dim3(256), 0, stream,
                     xbf, btb, s0, s1);
  hipLaunchKernelGGL(scan_kernel, dim3(Hdim / 256, Tdim / 32), dim3(256), 0, stream,
                     s0, s1, a, out);
}